// Round 2
// baseline (926.809 us; speedup 1.0000x reference)
//
#include <hip/hip_runtime.h>
#include <hip/hip_bf16.h>

#define D_MODEL 2048
#define SEQ     2048
#define BATCH   2
#define NH      16
#define HD      128
#define MROWS   (BATCH*SEQ)   // 4096

typedef __attribute__((ext_vector_type(8))) short bf16x8;
typedef __attribute__((ext_vector_type(4))) float f32x4;

// async global->LDS, 16B per lane. LDS dest is wave-uniform base + lane*16 (implicit).
static __device__ __forceinline__ void lds16(const void* g, void* l) {
    __builtin_amdgcn_global_load_lds(
        (const __attribute__((address_space(1))) void*)g,
        (__attribute__((address_space(3))) void*)l,
        16, 0, 0);
}

// f32 -> bf16 conversion, 4 elements/thread, fully coalesced.
__global__ __launch_bounds__(256) void cvt_f32_bf16(
    const float* __restrict__ in, unsigned short* __restrict__ out, const int n4)
{
    const int i = blockIdx.x*256 + threadIdx.x;
    if (i >= n4) return;
    const float4 a = ((const float4*)in)[i];
    ushort4 o;
    o.x = __bfloat16_as_ushort(__float2bfloat16(a.x));
    o.y = __bfloat16_as_ushort(__float2bfloat16(a.y));
    o.z = __bfloat16_as_ushort(__float2bfloat16(a.z));
    o.w = __bfloat16_as_ushort(__float2bfloat16(a.w));
    ((ushort4*)out)[i] = o;
}

// C[m][n] = sum_k A[m][k] * W[n][k] + bias[n]   (A:[M][K], W:[N][K] bf16, bias f32)
// 128x128 tile, BK=32, 4 waves (2x2), each wave 64x64 (4x4 frags of 16x16x32 MFMA).
template <typename OutT>
__global__ __launch_bounds__(256, 2) void gemm_bt_bias(
    const __hip_bfloat16* __restrict__ A,
    const __hip_bfloat16* __restrict__ W,
    const float* __restrict__ bias,
    OutT* __restrict__ C,
    const int M, const int N, const int K)
{
    __shared__ __hip_bfloat16 As[128*32];
    __shared__ __hip_bfloat16 Bs[128*32];
    const int nb   = N >> 7;
    const int bm   = blockIdx.x / nb;
    const int bn   = blockIdx.x % nb;
    const int tid  = threadIdx.x;
    const int lane = tid & 63;
    const int w    = tid >> 6;
    const int wr   = (w >> 1) * 64;
    const int wc   = (w & 1) * 64;
    const int l15  = lane & 15, l4 = lane >> 4;

    // staging: wave w covers tile rows [w*32, w*32+32), 2 instrs per operand
    const __hip_bfloat16* ga = A + (size_t)(bm*128 + w*32 + (lane>>2))*K + (lane&3)*8;
    const __hip_bfloat16* gb = W + (size_t)(bn*128 + w*32 + (lane>>2))*K + (lane&3)*8;
    __hip_bfloat16* lA0 = &As[(w*32)*32];
    __hip_bfloat16* lA1 = &As[(w*32+16)*32];
    __hip_bfloat16* lB0 = &Bs[(w*32)*32];
    __hip_bfloat16* lB1 = &Bs[(w*32+16)*32];

    f32x4 acc[4][4] = {};

    for (int kt = 0; kt < K; kt += 32) {
        __syncthreads();
        lds16(ga + kt,                 lA0);
        lds16(ga + kt + (size_t)16*K,  lA1);
        lds16(gb + kt,                 lB0);
        lds16(gb + kt + (size_t)16*K,  lB1);
        __syncthreads();
        bf16x8 af[4], bfr[4];
        #pragma unroll
        for (int i = 0; i < 4; i++) {
            af[i]  = *(const bf16x8*)&As[(wr + i*16 + l15)*32 + l4*8];
            bfr[i] = *(const bf16x8*)&Bs[(wc + i*16 + l15)*32 + l4*8];
        }
        #pragma unroll
        for (int i = 0; i < 4; i++)
            #pragma unroll
            for (int j = 0; j < 4; j++)
                acc[i][j] = __builtin_amdgcn_mfma_f32_16x16x32_bf16(af[i], bfr[j], acc[i][j], 0, 0, 0);
    }

    float bv[4];
    #pragma unroll
    for (int j = 0; j < 4; j++)
        bv[j] = bias[bn*128 + wc + j*16 + l15];
    #pragma unroll
    for (int i = 0; i < 4; i++) {
        #pragma unroll
        for (int j = 0; j < 4; j++) {
            const int col = bn*128 + wc + j*16 + l15;
            #pragma unroll
            for (int r = 0; r < 4; r++) {
                const int row = bm*128 + wr + i*16 + l4*4 + r;
                const float v = acc[i][j][r] + bv[j];
                if constexpr (sizeof(OutT) == 2)
                    C[(size_t)row*N + col] = OutT(__float2bfloat16(v));
                else
                    C[(size_t)row*N + col] = OutT(v);
            }
        }
    }
}

// sincos table: tab[s*256 + d] = cos(s*invf[d]), tab[s*256+128+d] = sin(...)
__global__ __launch_bounds__(256) void rope_table(float* __restrict__ tab)
{
    const int i = blockIdx.x*256 + threadIdx.x;   // 0 .. SEQ*HD-1
    const int s = i >> 7, d = i & 127;
    const float invf = expf(-(float)d * (9.210340371976184f / 1024.0f)); // 10000^(-d/1024)
    const float f = (float)s * invf;
    tab[(size_t)s*256 + d]       = cosf(f);
    tab[(size_t)s*256 + 128 + d] = sinf(f);
}

// interleaved-rotate_half RoPE, in place on bf16 projected activations.
// out[d]    = x[d]*cos[d]     - x[2d+1]*sin[d]       (d < 64)
// out[64+e] = x[64+e]*cos[..] + x[2e]*sin[..]        (e < 64)
__global__ __launch_bounds__(256) void rope_apply(
    __hip_bfloat16* __restrict__ X, const float* __restrict__ tab)
{
    const int tid  = threadIdx.x;
    const int w    = tid >> 6, lane = tid & 63;
    const int rowid = blockIdx.x*4 + w;          // bs*16 + h
    const int h  = rowid & 15;
    const int bs = rowid >> 4;
    const int s  = bs & (SEQ-1);
    __hip_bfloat16* base = X + (size_t)bs*D_MODEL + h*HD;
    const float v0 = __bfloat162float(base[lane]);
    const float v1 = __bfloat162float(base[lane+64]);
    const float* tc = tab + (size_t)s*256;
    const float c0 = tc[lane],    sn0 = tc[128+lane];
    const float c1 = tc[64+lane], sn1 = tc[192+lane];
    const float a0 = __shfl(v0, (2*lane+1) & 63);
    const float a1 = __shfl(v1, (2*lane+1) & 63);
    const float pA = (lane >= 32) ? a1 : a0;     // x[2*lane+1]
    const float b0 = __shfl(v0, (2*lane) & 63);
    const float b1 = __shfl(v1, (2*lane) & 63);
    const float pB = (lane >= 32) ? b1 : b0;     // x[2*lane]
    base[lane]    = __float2bfloat16(v0*c0 - pA*sn0);
    base[lane+64] = __float2bfloat16(v1*c1 + pB*sn1);
}

// V [B*S][D_MODEL] -> Vt [B*H][HD][SEQ]  (per-head transpose)
__global__ __launch_bounds__(256) void transpose_v(
    const unsigned short* __restrict__ V,
    unsigned short* __restrict__ Vt)
{
    __shared__ unsigned short t[64][66];
    const int bid = blockIdx.x;
    const int st = bid & 31;
    const int dt = (bid >> 5) & 1;
    const int bh = bid >> 6;
    const int b  = bh >> 4, h = bh & 15;
    const int tid = threadIdx.x;
    const int r = tid >> 5;
    const int c = tid & 31;
    #pragma unroll
    for (int i = 0; i < 8; i++) {
        const int row = i*8 + r;
        const unsigned int v = *(const unsigned int*)(
            V + (size_t)(b*SEQ + st*64 + row)*D_MODEL + h*HD + dt*64 + c*2);
        t[row][c*2]   = (unsigned short)(v & 0xffffu);
        t[row][c*2+1] = (unsigned short)(v >> 16);
    }
    __syncthreads();
    #pragma unroll
    for (int i = 0; i < 8; i++) {
        const int drow = i*8 + r;
        const unsigned int pk = (unsigned int)t[c*2][drow] | ((unsigned int)t[c*2+1][drow] << 16);
        *(unsigned int*)(Vt + ((size_t)bh*HD + dt*64 + drow)*SEQ + st*64 + c*2) = pk;
    }
}

// flash attention: 4 independent waves/block, each wave owns 16 q rows of one (b,h).
// KV chunk = 32. QK^T: A=Q frags (regs), B=K rows (global). PV: A=P (via LDS transpose),
// B=Vt rows (global, contiguous). Softmax state per lane: 4 rows (m, l).
__global__ __launch_bounds__(256) void flash_attn(
    const __hip_bfloat16* __restrict__ Q,
    const __hip_bfloat16* __restrict__ K,
    const __hip_bfloat16* __restrict__ Vt,
    __hip_bfloat16* __restrict__ ctx)
{
    __shared__ __hip_bfloat16 Pt[4][16*32];
    const int tid  = threadIdx.x;
    const int w    = tid >> 6;
    const int lane = tid & 63;
    const int l15  = lane & 15, l4 = lane >> 4;
    const int task = blockIdx.x*4 + w;           // 0..4095
    const int qt   = task & (SEQ/16 - 1);
    const int bh   = task >> 7;
    const int b    = bh >> 4, h = bh & 15;
    const int q0   = qt * 16;

    const __hip_bfloat16* qp = Q + (size_t)(b*SEQ + q0 + l15)*D_MODEL + h*HD + l4*8;
    bf16x8 aq[4];
    #pragma unroll
    for (int kc = 0; kc < 4; kc++) aq[kc] = *(const bf16x8*)(qp + kc*32);

    const __hip_bfloat16* kb = K  + (size_t)(b*SEQ + l15)*D_MODEL + h*HD + l4*8;
    const __hip_bfloat16* vb = Vt + ((size_t)bh*HD + l15)*SEQ + l4*8;

    f32x4 acco[8] = {};
    float mrun[4], lrun[4];
    #pragma unroll
    for (int r = 0; r < 4; r++) { mrun[r] = -1e30f; lrun[r] = 0.0f; }

    __hip_bfloat16* pt = &Pt[w][0];
    const float SC = 0.08838834764831845f;       // 1/sqrt(128)

    for (int kv = 0; kv < SEQ; kv += 32) {
        f32x4 s0 = {}, s1 = {};
        #pragma unroll
        for (int kc = 0; kc < 4; kc++) {
            const bf16x8 k0 = *(const bf16x8*)(kb + (size_t)(kv)*D_MODEL    + kc*32);
            const bf16x8 k1 = *(const bf16x8*)(kb + (size_t)(kv+16)*D_MODEL + kc*32);
            s0 = __builtin_amdgcn_mfma_f32_16x16x32_bf16(aq[kc], k0, s0, 0, 0, 0);
            s1 = __builtin_amdgcn_mfma_f32_16x16x32_bf16(aq[kc], k1, s1, 0, 0, 0);
        }
        #pragma unroll
        for (int r = 0; r < 4; r++) {
            const float v0 = s0[r]*SC, v1 = s1[r]*SC;
            float pm = fmaxf(v0, v1);
            #pragma unroll
            for (int m = 1; m < 16; m <<= 1) pm = fmaxf(pm, __shfl_xor(pm, m));
            const float mn = fmaxf(mrun[r], pm);
            const float al = __expf(mrun[r] - mn);
            const float e0 = __expf(v0 - mn), e1 = __expf(v1 - mn);
            float rs = e0 + e1;
            #pragma unroll
            for (int m = 1; m < 16; m <<= 1) rs += __shfl_xor(rs, m);
            lrun[r] = lrun[r]*al + rs;
            mrun[r] = mn;
            #pragma unroll
            for (int dt = 0; dt < 8; dt++) acco[dt][r] *= al;
            pt[(l4*4 + r)*32 + l15]      = __float2bfloat16(e0);
            pt[(l4*4 + r)*32 + 16 + l15] = __float2bfloat16(e1);
        }
        asm volatile("s_waitcnt lgkmcnt(0)" ::: "memory"); // drain P writes before transpose read
        const bf16x8 pa = *(const bf16x8*)&pt[l15*32 + l4*8];
        #pragma unroll
        for (int dt = 0; dt < 8; dt++) {
            const bf16x8 vv = *(const bf16x8*)(vb + (size_t)(dt*16)*SEQ + kv);
            acco[dt] = __builtin_amdgcn_mfma_f32_16x16x32_bf16(pa, vv, acco[dt], 0, 0, 0);
        }
    }

    float inv[4];
    #pragma unroll
    for (int r = 0; r < 4; r++) inv[r] = 1.0f / lrun[r];
    __hip_bfloat16* cp = ctx + (size_t)(b*SEQ + q0 + l4*4)*D_MODEL + h*HD + l15;
    #pragma unroll
    for (int dt = 0; dt < 8; dt++)
        #pragma unroll
        for (int r = 0; r < 4; r++)
            cp[(size_t)r*D_MODEL + dt*16] = __float2bfloat16(acco[dt][r]*inv[r]);
}

extern "C" void kernel_launch(void* const* d_in, const int* in_sizes, int n_in,
                              void* d_out, int out_size, void* d_ws, size_t ws_size,
                              hipStream_t stream)
{
    const float* query = (const float*)d_in[0];
    const float* key   = (const float*)d_in[1];
    const float* value = (const float*)d_in[2];
    const float* Wq    = (const float*)d_in[3];
    const float* bq    = (const float*)d_in[4];
    const float* Wk    = (const float*)d_in[5];
    const float* bk    = (const float*)d_in[6];
    const float* Wv    = (const float*)d_in[7];
    const float* bv    = (const float*)d_in[8];
    const float* Wo    = (const float*)d_in[9];
    const float* bo    = (const float*)d_in[10];
    float* out = (float*)d_out;

    char* ws = (char*)d_ws;
    const size_t MB = 1024*1024;
    __hip_bfloat16* qb  = (__hip_bfloat16*)(ws);            // 16 MiB each activation
    __hip_bfloat16* kbuf= (__hip_bfloat16*)(ws + 16*MB);
    __hip_bfloat16* vbuf= (__hip_bfloat16*)(ws + 32*MB);
    __hip_bfloat16* Qp  = (__hip_bfloat16*)(ws + 48*MB);
    __hip_bfloat16* Kp  = (__hip_bfloat16*)(ws + 64*MB);
    __hip_bfloat16* Vp  = (__hip_bfloat16*)(ws + 80*MB);
    __hip_bfloat16* Vt  = (__hip_bfloat16*)(ws + 96*MB);
    __hip_bfloat16* ctx = (__hip_bfloat16*)(ws + 112*MB);
    __hip_bfloat16* Wqb = (__hip_bfloat16*)(ws + 128*MB);   // 8 MiB each weight
    __hip_bfloat16* Wkb = (__hip_bfloat16*)(ws + 136*MB);
    __hip_bfloat16* Wvb = (__hip_bfloat16*)(ws + 144*MB);
    __hip_bfloat16* Wob = (__hip_bfloat16*)(ws + 152*MB);
    float*          tab = (float*)         (ws + 160*MB);   // 2 MiB

    const int nA4 = MROWS*D_MODEL/4;    // 2,097,152
    const int nW4 = D_MODEL*D_MODEL/4;  // 1,048,576
    cvt_f32_bf16<<<nA4/256, 256, 0, stream>>>(query, (unsigned short*)qb,   nA4);
    cvt_f32_bf16<<<nA4/256, 256, 0, stream>>>(key,   (unsigned short*)kbuf, nA4);
    cvt_f32_bf16<<<nA4/256, 256, 0, stream>>>(value, (unsigned short*)vbuf, nA4);
    cvt_f32_bf16<<<nW4/256, 256, 0, stream>>>(Wq,    (unsigned short*)Wqb,  nW4);
    cvt_f32_bf16<<<nW4/256, 256, 0, stream>>>(Wk,    (unsigned short*)Wkb,  nW4);
    cvt_f32_bf16<<<nW4/256, 256, 0, stream>>>(Wv,    (unsigned short*)Wvb,  nW4);
    cvt_f32_bf16<<<nW4/256, 256, 0, stream>>>(Wo,    (unsigned short*)Wob,  nW4);

    rope_table<<<SEQ*HD/256, 256, 0, stream>>>(tab);

    const int gemm_grid = (MROWS/128)*(D_MODEL/128);
    gemm_bt_bias<__hip_bfloat16><<<gemm_grid, 256, 0, stream>>>(qb,   Wqb, bq, Qp, MROWS, D_MODEL, D_MODEL);
    gemm_bt_bias<__hip_bfloat16><<<gemm_grid, 256, 0, stream>>>(kbuf, Wkb, bk, Kp, MROWS, D_MODEL, D_MODEL);
    gemm_bt_bias<__hip_bfloat16><<<gemm_grid, 256, 0, stream>>>(vbuf, Wvb, bv, Vp, MROWS, D_MODEL, D_MODEL);

    rope_apply<<<BATCH*SEQ*NH/4, 256, 0, stream>>>(Qp, tab);
    rope_apply<<<BATCH*SEQ*NH/4, 256, 0, stream>>>(Kp, tab);
    transpose_v<<<BATCH*NH*2*(SEQ/64), 256, 0, stream>>>((const unsigned short*)Vp, (unsigned short*)Vt);
    flash_attn<<<BATCH*NH*(SEQ/16)/4, 256, 0, stream>>>(Qp, Kp, Vt, ctx);

    gemm_bt_bias<float><<<gemm_grid, 256, 0, stream>>>(ctx, Wob, bo, out, MROWS, D_MODEL, D_MODEL);
}

// Round 3
// 378.269 us; speedup vs baseline: 2.4501x; 2.4501x over previous
//
#include <hip/hip_runtime.h>
#include <hip/hip_bf16.h>

#define D_MODEL 2048
#define SEQ     2048
#define BATCH   2
#define NH      16
#define HD      128
#define MROWS   (BATCH*SEQ)   // 4096

typedef __attribute__((ext_vector_type(8)))  short bf16x8;
typedef __attribute__((ext_vector_type(4)))  float f32x4;
typedef __attribute__((ext_vector_type(16))) float f32x16;
typedef __attribute__((ext_vector_type(4)))  unsigned int u32x4;

// async global->LDS, 16B per lane. LDS dest is wave-uniform base + lane*16 (implicit).
static __device__ __forceinline__ void lds16(const void* g, void* l) {
    __builtin_amdgcn_global_load_lds(
        (const __attribute__((address_space(1))) void*)g,
        (__attribute__((address_space(3))) void*)l,
        16, 0, 0);
}

static __device__ __forceinline__ unsigned int pk2(float a, float b) {
    const unsigned int lo = __bfloat16_as_ushort(__float2bfloat16(a));
    const unsigned int hh = __bfloat16_as_ushort(__float2bfloat16(b));
    return lo | (hh << 16);
}

// f32 -> bf16 conversion, 4 elements/thread, fully coalesced.
__global__ __launch_bounds__(256) void cvt_f32_bf16(
    const float* __restrict__ in, unsigned short* __restrict__ out, const int n4)
{
    const int i = blockIdx.x*256 + threadIdx.x;
    if (i >= n4) return;
    const float4 a = ((const float4*)in)[i];
    ushort4 o;
    o.x = __bfloat16_as_ushort(__float2bfloat16(a.x));
    o.y = __bfloat16_as_ushort(__float2bfloat16(a.y));
    o.z = __bfloat16_as_ushort(__float2bfloat16(a.z));
    o.w = __bfloat16_as_ushort(__float2bfloat16(a.w));
    ((ushort4*)out)[i] = o;
}

// C[m][n] = sum_k A[m][k] * W[n][k] + bias[n]   (A:[M][K], W:[N][K] bf16, bias f32)
template <typename OutT>
__global__ __launch_bounds__(256, 2) void gemm_bt_bias(
    const __hip_bfloat16* __restrict__ A,
    const __hip_bfloat16* __restrict__ W,
    const float* __restrict__ bias,
    OutT* __restrict__ C,
    const int M, const int N, const int K)
{
    __shared__ __hip_bfloat16 As[128*32];
    __shared__ __hip_bfloat16 Bs[128*32];
    const int nb   = N >> 7;
    const int bm   = blockIdx.x / nb;
    const int bn   = blockIdx.x % nb;
    const int tid  = threadIdx.x;
    const int lane = tid & 63;
    const int w    = tid >> 6;
    const int wr   = (w >> 1) * 64;
    const int wc   = (w & 1) * 64;
    const int l15  = lane & 15, l4 = lane >> 4;

    const __hip_bfloat16* ga = A + (size_t)(bm*128 + w*32 + (lane>>2))*K + (lane&3)*8;
    const __hip_bfloat16* gb = W + (size_t)(bn*128 + w*32 + (lane>>2))*K + (lane&3)*8;
    __hip_bfloat16* lA0 = &As[(w*32)*32];
    __hip_bfloat16* lA1 = &As[(w*32+16)*32];
    __hip_bfloat16* lB0 = &Bs[(w*32)*32];
    __hip_bfloat16* lB1 = &Bs[(w*32+16)*32];

    f32x4 acc[4][4] = {};

    for (int kt = 0; kt < K; kt += 32) {
        __syncthreads();
        lds16(ga + kt,                 lA0);
        lds16(ga + kt + (size_t)16*K,  lA1);
        lds16(gb + kt,                 lB0);
        lds16(gb + kt + (size_t)16*K,  lB1);
        __syncthreads();
        bf16x8 af[4], bfr[4];
        #pragma unroll
        for (int i = 0; i < 4; i++) {
            af[i]  = *(const bf16x8*)&As[(wr + i*16 + l15)*32 + l4*8];
            bfr[i] = *(const bf16x8*)&Bs[(wc + i*16 + l15)*32 + l4*8];
        }
        #pragma unroll
        for (int i = 0; i < 4; i++)
            #pragma unroll
            for (int j = 0; j < 4; j++)
                acc[i][j] = __builtin_amdgcn_mfma_f32_16x16x32_bf16(af[i], bfr[j], acc[i][j], 0, 0, 0);
    }

    float bv[4];
    #pragma unroll
    for (int j = 0; j < 4; j++)
        bv[j] = bias[bn*128 + wc + j*16 + l15];
    #pragma unroll
    for (int i = 0; i < 4; i++) {
        #pragma unroll
        for (int j = 0; j < 4; j++) {
            const int col = bn*128 + wc + j*16 + l15;
            #pragma unroll
            for (int r = 0; r < 4; r++) {
                const int row = bm*128 + wr + i*16 + l4*4 + r;
                const float v = acc[i][j][r] + bv[j];
                if constexpr (sizeof(OutT) == 2)
                    C[(size_t)row*N + col] = OutT(__float2bfloat16(v));
                else
                    C[(size_t)row*N + col] = OutT(v);
            }
        }
    }
}

// sincos table: tab[s*256 + d] = cos(s*invf[d]), tab[s*256+128+d] = sin(...)
__global__ __launch_bounds__(256) void rope_table(float* __restrict__ tab)
{
    const int i = blockIdx.x*256 + threadIdx.x;
    const int s = i >> 7, d = i & 127;
    const float invf = expf(-(float)d * (9.210340371976184f / 1024.0f));
    const float f = (float)s * invf;
    tab[(size_t)s*256 + d]       = cosf(f);
    tab[(size_t)s*256 + 128 + d] = sinf(f);
}

// interleaved-rotate_half RoPE, in place on bf16 projected activations.
__global__ __launch_bounds__(256) void rope_apply(
    __hip_bfloat16* __restrict__ X, const float* __restrict__ tab)
{
    const int tid  = threadIdx.x;
    const int w    = tid >> 6, lane = tid & 63;
    const int rowid = blockIdx.x*4 + w;
    const int h  = rowid & 15;
    const int bs = rowid >> 4;
    const int s  = bs & (SEQ-1);
    __hip_bfloat16* base = X + (size_t)bs*D_MODEL + h*HD;
    const float v0 = __bfloat162float(base[lane]);
    const float v1 = __bfloat162float(base[lane+64]);
    const float* tc = tab + (size_t)s*256;
    const float c0 = tc[lane],    sn0 = tc[128+lane];
    const float c1 = tc[64+lane], sn1 = tc[192+lane];
    const float a0 = __shfl(v0, (2*lane+1) & 63);
    const float a1 = __shfl(v1, (2*lane+1) & 63);
    const float pA = (lane >= 32) ? a1 : a0;
    const float b0 = __shfl(v0, (2*lane) & 63);
    const float b1 = __shfl(v1, (2*lane) & 63);
    const float pB = (lane >= 32) ? b1 : b0;
    base[lane]    = __float2bfloat16(v0*c0 - pA*sn0);
    base[lane+64] = __float2bfloat16(v1*c1 + pB*sn1);
}

// V [B*S][D_MODEL] -> Vt [B*H][HD][SEQ]  (per-head transpose)
__global__ __launch_bounds__(256) void transpose_v(
    const unsigned short* __restrict__ V,
    unsigned short* __restrict__ Vt)
{
    __shared__ unsigned short t[64][66];
    const int bid = blockIdx.x;
    const int st = bid & 31;
    const int dt = (bid >> 5) & 1;
    const int bh = bid >> 6;
    const int b  = bh >> 4, h = bh & 15;
    const int tid = threadIdx.x;
    const int r = tid >> 5;
    const int c = tid & 31;
    #pragma unroll
    for (int i = 0; i < 8; i++) {
        const int row = i*8 + r;
        const unsigned int v = *(const unsigned int*)(
            V + (size_t)(b*SEQ + st*64 + row)*D_MODEL + h*HD + dt*64 + c*2);
        t[row][c*2]   = (unsigned short)(v & 0xffffu);
        t[row][c*2+1] = (unsigned short)(v >> 16);
    }
    __syncthreads();
    #pragma unroll
    for (int i = 0; i < 8; i++) {
        const int drow = i*8 + r;
        const unsigned int pk = (unsigned int)t[c*2][drow] | ((unsigned int)t[c*2+1][drow] << 16);
        *(unsigned int*)(Vt + ((size_t)bh*HD + dt*64 + drow)*SEQ + st*64 + c*2) = pk;
    }
}

// ---------------------------------------------------------------------------
// Flash attention, 32x32x16 MFMA, swapped-QK^T, in-register softmax.
// Block: 256 threads = 4 waves; block owns (bh, 128 q rows); wave owns 32 q.
// KV chunk 64, K[64][128] + Vt[128][64] LDS-staged (XOR-swizzled), dbuf.
// ---------------------------------------------------------------------------
__global__ __launch_bounds__(256, 2) void flash_attn(
    const __hip_bfloat16* __restrict__ Qg,
    const __hip_bfloat16* __restrict__ Kg,
    const __hip_bfloat16* __restrict__ Vtg,
    __hip_bfloat16* __restrict__ ctx)
{
    __shared__ __hip_bfloat16 Ks[2][64*128];   // 32 KB (swizzled slots: ^ (row&15))
    __shared__ __hip_bfloat16 Vs[2][128*64];   // 32 KB (swizzled slots: ^ (row&7))

    const int tid  = threadIdx.x;
    const int w    = tid >> 6;           // wave 0..3
    const int lane = tid & 63;
    const int l31  = lane & 31;
    const int hi   = lane >> 5;          // 0/1
    const bool hib = (hi != 0);

    const int bid0 = blockIdx.x;                     // 512 blocks
    const int bid  = (bid0 & 7)*64 + (bid0 >> 3);    // XCD-aware swizzle (bijective)
    const int bh   = bid >> 4;                       // 0..31
    const int qt   = bid & 15;
    const int bi   = bh >> 4, h = bh & 15;
    const int q0   = qt * 128;

    const float SC = 0.08838834764831845f;   // 1/sqrt(128)

    // Q fragments: wave's 32 q rows, 8 d-slices of 16. B-frag: n=q=l31, k=d ofs hi*8.
    bf16x8 aq[8];
    {
        const __hip_bfloat16* qp =
            Qg + (size_t)(bi*SEQ + q0 + w*32 + l31)*D_MODEL + h*HD + hi*8;
        #pragma unroll
        for (int ds = 0; ds < 8; ds++) aq[ds] = *(const bf16x8*)(qp + ds*16);
    }

    // stage K chunk rows [w*16,w*16+16) and Vt chunk rows [w*32,w*32+32)
    // linear LDS dest + inverse-swizzled global source (involution XOR).
#define STAGE(NB, KV) do {                                                              \
        _Pragma("unroll")                                                               \
        for (int i_ = 0; i_ < 4; i_++) {                                                \
            const int kr_ = w*16 + i_*4 + (lane>>4);                                    \
            lds16(Kg + (size_t)(bi*SEQ + (KV) + kr_)*D_MODEL + h*HD                     \
                      + (((lane&15) ^ (kr_&15))*8),                                     \
                  &Ks[NB][(w*16 + i_*4)*128]);                                          \
        }                                                                               \
        _Pragma("unroll")                                                               \
        for (int i_ = 0; i_ < 4; i_++) {                                                \
            const int vr_ = w*32 + i_*8 + (lane>>3);                                    \
            lds16(Vtg + ((size_t)bh*HD + vr_)*SEQ + (KV)                                \
                      + (((lane&7) ^ (lane>>3))*8),                                     \
                  &Vs[NB][(w*32 + i_*8)*64]);                                           \
        }                                                                               \
    } while (0)

    f32x16 o0 = {}, o1 = {}, o2 = {}, o3 = {};
    float m_run = -1e30f, l_run = 0.0f;

    STAGE(0, 0);

    for (int t = 0; t < SEQ/64; t++) {
        const int cb = t & 1;
        __syncthreads();                      // stage(t) visible; buf cb^1 free
        if (t < SEQ/64 - 1) STAGE(cb^1, (t+1)*64);

        // ---- QK^T (swapped): S^T = mfma(A=K rows, B=Q rows) ----
        // p0: k 0..31, p1: k 32..63. lane: col q=l31; rows k=(r&3)+8*(r>>2)+4*hi.
        f32x16 p0 = {}, p1 = {};
        #pragma unroll
        for (int ds = 0; ds < 8; ds++) {
            const int sl = ((ds*2 + hi) ^ (lane&15)) * 8;
            const bf16x8 k0 = *(const bf16x8*)&Ks[cb][l31*128 + sl];
            const bf16x8 k1 = *(const bf16x8*)&Ks[cb][(32 + l31)*128 + sl];
            p0 = __builtin_amdgcn_mfma_f32_32x32x16_bf16(k0, aq[ds], p0, 0, 0, 0);
            p1 = __builtin_amdgcn_mfma_f32_32x32x16_bf16(k1, aq[ds], p1, 0, 0, 0);
        }

        // ---- online softmax (raw-domain max; SC folded into exp args) ----
        float pm = fmaxf(p0[0], p1[0]);
        #pragma unroll
        for (int r = 1; r < 16; r++) pm = fmaxf(pm, fmaxf(p0[r], p1[r]));
        pm = fmaxf(pm, __shfl_xor(pm, 32));

        // defer-max (T13): raw THR = 8/SC = 90.51
        if (!__all(pm <= m_run + 90.509667f)) {
            const float mnew = fmaxf(m_run, pm);
            const float al = __expf((m_run - mnew) * SC);
            l_run *= al;
            m_run = mnew;
            float alr[16];
            #pragma unroll
            for (int r = 0; r < 16; r++)
                alr[r] = __shfl(al, (r&3) + 8*(r>>2) + (hib ? 4 : 0));
            #pragma unroll
            for (int r = 0; r < 16; r++) {
                o0[r] *= alr[r]; o1[r] *= alr[r]; o2[r] *= alr[r]; o3[r] *= alr[r];
            }
        }

        #pragma unroll
        for (int r = 0; r < 16; r++) {
            p0[r] = __expf((p0[r] - m_run) * SC);
            p1[r] = __expf((p1[r] - m_run) * SC);
        }
        float rs = 0.0f;
        #pragma unroll
        for (int r = 0; r < 16; r++) rs += p0[r] + p1[r];
        rs += __shfl_xor(rs, 32);
        l_run += rs;

        // ---- PV: O += P·V. A=P rows q (l31), B=Vt rows d. k-slice ks of 16. ----
        // in-register P repack: own-half packs + shfl_xor(32) exchange.
#define PV_STEP(PF, KS) do {                                                            \
            const unsigned int A0_ = pk2(PF[8*((KS)&1)+0], PF[8*((KS)&1)+1]);           \
            const unsigned int A1_ = pk2(PF[8*((KS)&1)+2], PF[8*((KS)&1)+3]);           \
            const unsigned int B0_ = pk2(PF[8*((KS)&1)+4], PF[8*((KS)&1)+5]);           \
            const unsigned int B1_ = pk2(PF[8*((KS)&1)+6], PF[8*((KS)&1)+7]);           \
            const unsigned int s0_ = hib ? A0_ : B0_;                                   \
            const unsigned int s1_ = hib ? A1_ : B1_;                                   \
            const unsigned int r0_ = (unsigned int)__shfl_xor((int)s0_, 32);            \
            const unsigned int r1_ = (unsigned int)__shfl_xor((int)s1_, 32);            \
            u32x4 au_;                                                                  \
            au_.x = hib ? r0_ : A0_;  au_.y = hib ? r1_ : A1_;                          \
            au_.z = hib ? B0_ : r0_;  au_.w = hib ? B1_ : r1_;                          \
            const bf16x8 pa_ = *(const bf16x8*)&au_;                                    \
            const int ko_ = (((KS)*2 + hi) ^ (lane&7)) * 8;                             \
            o0 = __builtin_amdgcn_mfma_f32_32x32x16_bf16(pa_,                           \
                     *(const bf16x8*)&Vs[cb][(  0 + l31)*64 + ko_], o0, 0, 0, 0);       \
            o1 = __builtin_amdgcn_mfma_f32_32x32x16_bf16(pa_,                           \
                     *(const bf16x8*)&Vs[cb][( 32 + l31)*64 + ko_], o1, 0, 0, 0);       \
            o2 = __builtin_amdgcn_mfma_f32_32x32x16_bf16(pa_,                           \
                     *(const bf16x8*)&Vs[cb][( 64 + l31)*64 + ko_], o2, 0, 0, 0);       \
            o3 = __builtin_amdgcn_mfma_f32_32x32x16_bf16(pa_,                           \
                     *(const bf16x8*)&Vs[cb][( 96 + l31)*64 + ko_], o3, 0, 0, 0);       \
        } while (0)

        PV_STEP(p0, 0); PV_STEP(p0, 1); PV_STEP(p1, 2); PV_STEP(p1, 3);
#undef PV_STEP
    }

    // ---- epilogue: normalize + store. O frag: col=d=l31, row pattern = q. ----
    const float inv = 1.0f / l_run;
    float invr[16];
    #pragma unroll
    for (int r = 0; r < 16; r++)
        invr[r] = __shfl(inv, (r&3) + 8*(r>>2) + (hib ? 4 : 0));

    #pragma unroll
    for (int r = 0; r < 16; r++) {
        const int qr = q0 + w*32 + (r&3) + 8*(r>>2) + (hib ? 4 : 0);
        __hip_bfloat16* cp = ctx + (size_t)(bi*SEQ + qr)*D_MODEL + h*HD + l31;
        cp[0]  = __float2bfloat16(o0[r] * invr[r]);
        cp[32] = __float2bfloat16(o1[r] * invr[r]);
        cp[64] = __float2bfloat16(o2[r] * invr[r]);
        cp[96] = __float2bfloat16(o3[r] * invr[r]);
    }
#undef STAGE
}

extern "C" void kernel_launch(void* const* d_in, const int* in_sizes, int n_in,
                              void* d_out, int out_size, void* d_ws, size_t ws_size,
                              hipStream_t stream)
{
    const float* query = (const float*)d_in[0];
    const float* key   = (const float*)d_in[1];
    const float* value = (const float*)d_in[2];
    const float* Wq    = (const float*)d_in[3];
    const float* bq    = (const float*)d_in[4];
    const float* Wk    = (const float*)d_in[5];
    const float* bk    = (const float*)d_in[6];
    const float* Wv    = (const float*)d_in[7];
    const float* bv    = (const float*)d_in[8];
    const float* Wo    = (const float*)d_in[9];
    const float* bo    = (const float*)d_in[10];
    float* out = (float*)d_out;

    char* ws = (char*)d_ws;
    const size_t MB = 1024*1024;
    __hip_bfloat16* qb  = (__hip_bfloat16*)(ws);
    __hip_bfloat16* kbuf= (__hip_bfloat16*)(ws + 16*MB);
    __hip_bfloat16* vbuf= (__hip_bfloat16*)(ws + 32*MB);
    __hip_bfloat16* Qp  = (__hip_bfloat16*)(ws + 48*MB);
    __hip_bfloat16* Kp  = (__hip_bfloat16*)(ws + 64*MB);
    __hip_bfloat16* Vp  = (__hip_bfloat16*)(ws + 80*MB);
    __hip_bfloat16* Vt  = (__hip_bfloat16*)(ws + 96*MB);
    __hip_bfloat16* ctx = (__hip_bfloat16*)(ws + 112*MB);
    __hip_bfloat16* Wqb = (__hip_bfloat16*)(ws + 128*MB);
    __hip_bfloat16* Wkb = (__hip_bfloat16*)(ws + 136*MB);
    __hip_bfloat16* Wvb = (__hip_bfloat16*)(ws + 144*MB);
    __hip_bfloat16* Wob = (__hip_bfloat16*)(ws + 152*MB);
    float*          tab = (float*)         (ws + 160*MB);

    const int nA4 = MROWS*D_MODEL/4;
    const int nW4 = D_MODEL*D_MODEL/4;
    cvt_f32_bf16<<<nA4/256, 256, 0, stream>>>(query, (unsigned short*)qb,   nA4);
    cvt_f32_bf16<<<nA4/256, 256, 0, stream>>>(key,   (unsigned short*)kbuf, nA4);
    cvt_f32_bf16<<<nA4/256, 256, 0, stream>>>(value, (unsigned short*)vbuf, nA4);
    cvt_f32_bf16<<<nW4/256, 256, 0, stream>>>(Wq,    (unsigned short*)Wqb,  nW4);
    cvt_f32_bf16<<<nW4/256, 256, 0, stream>>>(Wk,    (unsigned short*)Wkb,  nW4);
    cvt_f32_bf16<<<nW4/256, 256, 0, stream>>>(Wv,    (unsigned short*)Wvb,  nW4);
    cvt_f32_bf16<<<nW4/256, 256, 0, stream>>>(Wo,    (unsigned short*)Wob,  nW4);

    rope_table<<<SEQ*HD/256, 256, 0, stream>>>(tab);

    const int gemm_grid = (MROWS/128)*(D_MODEL/128);
    gemm_bt_bias<__hip_bfloat16><<<gemm_grid, 256, 0, stream>>>(qb,   Wqb, bq, Qp, MROWS, D_MODEL, D_MODEL);
    gemm_bt_bias<__hip_bfloat16><<<gemm_grid, 256, 0, stream>>>(kbuf, Wkb, bk, Kp, MROWS, D_MODEL, D_MODEL);
    gemm_bt_bias<__hip_bfloat16><<<gemm_grid, 256, 0, stream>>>(vbuf, Wvb, bv, Vp, MROWS, D_MODEL, D_MODEL);

    rope_apply<<<BATCH*SEQ*NH/4, 256, 0, stream>>>(Qp, tab);
    rope_apply<<<BATCH*SEQ*NH/4, 256, 0, stream>>>(Kp, tab);
    transpose_v<<<BATCH*NH*2*(SEQ/64), 256, 0, stream>>>((const unsigned short*)Vp, (unsigned short*)Vt);

    flash_attn<<<NH*BATCH*(SEQ/128), 256, 0, stream>>>(Qp, Kp, Vt, ctx);

    gemm_bt_bias<float><<<gemm_grid, 256, 0, stream>>>(ctx, Wob, bo, out, MROWS, D_MODEL, D_MODEL);
}